// Round 7
// baseline (289.408 us; speedup 1.0000x reference)
//
#include <hip/hip_runtime.h>
#include <hip/hip_bf16.h>

#define BB 4
#define SS 2048
#define DD 1024
#define HH 16
#define MM (BB * SS)   // 8192

typedef __attribute__((ext_vector_type(8))) short bf16x8;
typedef __attribute__((ext_vector_type(4))) float f32x4;

__device__ __forceinline__ unsigned short f2bf(float f) {
  union { float f; unsigned u; } v; v.f = f;
  unsigned r = v.u + 0x7fffu + ((v.u >> 16) & 1u);
  return (unsigned short)(r >> 16);
}

__device__ __forceinline__ void gl2lds16(const void* g, void* l) {
  __builtin_amdgcn_global_load_lds(
      (const __attribute__((address_space(1))) unsigned int*)g,
      (__attribute__((address_space(3))) unsigned int*)l, 16, 0, 0);
}

// fp32 -> bf16 pre-convert: y<4 -> W[y] (1M each), y>=4 -> X chunk (8M total)
__global__ __launch_bounds__(256)
void convall(const float* __restrict__ X, const float* __restrict__ a,
             const float* __restrict__ b, const float* __restrict__ c,
             const float* __restrict__ d, unsigned short* __restrict__ wall,
             unsigned short* __restrict__ xb) {
  int y = blockIdx.y;
  const float* s; unsigned short* o;
  if (y < 4) {
    const float* srcs[4] = {a, b, c, d};
    s = srcs[y]; o = wall + (size_t)y * 1048576;
  } else {
    s = X + (size_t)(y - 4) * 1048576; o = xb + (size_t)(y - 4) * 1048576;
  }
  int i = (blockIdx.x * 256 + threadIdx.x) * 4;
  float4 v = *(const float4*)(s + i);
  ushort4 h4; h4.x = f2bf(v.x); h4.y = f2bf(v.y); h4.z = f2bf(v.z); h4.w = f2bf(v.w);
  *(ushort4*)(o + i) = h4;
}

// C[m,n] = sum_k A[m,k]*W[n,k].  A bf16, B bf16, both staged via global_load_lds w=16.
// OMODE 1: fp32 C.  OMODE 3: QKV routing (Q bf16 / K bf16 / V -> sigma-permuted V^T,
// Vt[bh][d][kt*64 + sigma(key)], sigma(key) = (key&15)*4 + (key>>4)).
template<int OMODE>
__global__ __launch_bounds__(256)
void gemm_k(const unsigned short* __restrict__ A16, const unsigned short* __restrict__ Bp,
            void* __restrict__ C0p, void* __restrict__ C1p, void* __restrict__ C2p) {
  __shared__ unsigned short As[32 * 136];  // staging [128][32]; also V^T transpose buf
  __shared__ unsigned short Bs[128 * 32];
  const int m0 = blockIdx.x * 128, n0g = blockIdx.y * 128;
  const int tid = threadIdx.x, lane = tid & 63, wave = tid >> 6;
  const int wm = (wave & 1) * 64, wn = (wave >> 1) * 64;
  const int row_in = lane & 15, quad = lane >> 4;

  f32x4 acc[4][4] = {};

  for (int kb = 0; kb < DD; kb += 32) {
    {
      int r = wave * 32 + (lane >> 2);
      const unsigned short* g = Bp + (size_t)(n0g + r) * DD + kb + (lane & 3) * 8;
      gl2lds16(g, Bs + (wave * 32) * 32);
      gl2lds16(g + (size_t)16 * DD, Bs + (wave * 32 + 16) * 32);
      const unsigned short* ga = A16 + (size_t)(m0 + r) * DD + kb + (lane & 3) * 8;
      gl2lds16(ga, As + (wave * 32) * 32);
      gl2lds16(ga + (size_t)16 * DD, As + (wave * 32 + 16) * 32);
    }
    __syncthreads();
    bf16x8 af[4], bfr[4];
#pragma unroll
    for (int i = 0; i < 4; ++i)
      af[i] = *(const bf16x8*)(As + (wm + i * 16 + row_in) * 32 + quad * 8);
#pragma unroll
    for (int j = 0; j < 4; ++j)
      bfr[j] = *(const bf16x8*)(Bs + (wn + j * 16 + row_in) * 32 + quad * 8);
#pragma unroll
    for (int i = 0; i < 4; ++i)
#pragma unroll
      for (int j = 0; j < 4; ++j)
        acc[i][j] = __builtin_amdgcn_mfma_f32_16x16x32_bf16(af[i], bfr[j], acc[i][j], 0, 0, 0);
    __syncthreads();
  }

  // C/D layout: col = lane&15, row = quad*4 + reg
  if (OMODE == 1) {
    float* Cout = (float*)C0p;
#pragma unroll
    for (int i = 0; i < 4; ++i)
#pragma unroll
      for (int j = 0; j < 4; ++j)
#pragma unroll
        for (int r = 0; r < 4; ++r)
          Cout[(size_t)(m0 + wm + i * 16 + quad * 4 + r) * DD + n0g + wn + j * 16 + row_in] =
              acc[i][j][r];
  } else {
    const int seg = n0g >> 10;
    if (seg < 2) {
      unsigned short* Cout = (unsigned short*)(seg == 0 ? C0p : C1p);
      const int n0 = n0g & 1023;
#pragma unroll
      for (int i = 0; i < 4; ++i)
#pragma unroll
        for (int j = 0; j < 4; ++j)
#pragma unroll
          for (int r = 0; r < 4; ++r)
            Cout[(size_t)(m0 + wm + i * 16 + quad * 4 + r) * DD + n0 + wn + j * 16 + row_in] =
                f2bf(acc[i][j][r]);
    } else {
      // V^T epilogue -> Vt[bh][d][kt*64 + sigma(key)].  Stored position p holds
      // key sigma^-1(p) = (p&3)*16 + (p>>2): gather cols from the transpose buffer.
      unsigned short* Vt = (unsigned short*)C2p;
      unsigned short* Ts = As;
      const int b = m0 >> 11, m_in_b = m0 & 2047;
      const int nv = n0g - 2048;
#pragma unroll
      for (int cn = 0; cn < 4; ++cn) {
        if ((wave >> 1) == (cn >> 1)) {
#pragma unroll
          for (int i = 0; i < 4; ++i)
#pragma unroll
            for (int jj = 0; jj < 2; ++jj)
#pragma unroll
              for (int r = 0; r < 4; ++r) {
                int j = (cn & 1) * 2 + jj;
                Ts[(jj * 16 + row_in) * 136 + wm + i * 16 + quad * 4 + r] = f2bf(acc[i][j][r]);
              }
        }
        __syncthreads();
#pragma unroll
        for (int it = 0; it < 2; ++it) {
          int cc = tid + it * 256;
          int rowL = cc >> 4, o8 = (cc & 15) * 8;
          int cbase = rowL * 136 + (o8 & 64) + ((o8 & 63) >> 2);
          ushort4 lo, hi;
          lo.x = Ts[cbase];      lo.y = Ts[cbase + 16];
          lo.z = Ts[cbase + 32]; lo.w = Ts[cbase + 48];
          hi.x = Ts[cbase + 1];  hi.y = Ts[cbase + 17];
          hi.z = Ts[cbase + 33]; hi.w = Ts[cbase + 49];
          int n = nv + cn * 32 + rowL;
          int h = n >> 6, dd = n & 63;
          unsigned short* dst = Vt + ((size_t)((b * 16 + h) * 64 + dd)) * SS + m_in_b + o8;
          *(ushort4*)dst = lo;
          *(ushort4*)(dst + 4) = hi;
        }
        __syncthreads();
      }
    }
  }
}

// Flash attention: block = 256 q-rows x one (b,h); 4 waves x 64 q-rows.
// Staging identical to the proven R6 pattern (plain vector copies, stride-72 LDS);
// V sigma-pre-permuted in global.  Fixed-shift softmax; bk frags cached in regs
// and amortized over 4 m-tiles.  AO written in-place over Q.
__global__ __launch_bounds__(256, 2)
void attn_kernel(const unsigned short* __restrict__ Q, const unsigned short* __restrict__ K,
                 const unsigned short* __restrict__ Vt_g, unsigned short* __restrict__ AO) {
  __shared__ unsigned short Ks[64 * 72];   // [key][d]
  __shared__ unsigned short Vs[64 * 72];   // [d][sigma(key)]
  __shared__ unsigned short Ps[256 * 72];  // [q perm][sigma(key)], 64-row wave stripes
  const int qt = blockIdx.x, bh = blockIdx.y, b = bh >> 4, h = bh & 15;
  const int tid = threadIdx.x, lane = tid & 63, w = tid >> 6;
  const int row_in = lane & 15, quad = lane >> 4;
  const float Cs = 0.180336880f;   // log2e / 8
  const float C0 = 17.3123405f;    // 12 * log2e
  const size_t qbase = ((size_t)(b * SS + qt * 256)) * DD + h * 64;

  bf16x8 aq[4][2];
#pragma unroll
  for (int m = 0; m < 4; ++m) {
    const unsigned short* qp = Q + qbase + (size_t)(w * 64 + m * 16 + row_in) * DD;
    aq[m][0] = *(const bf16x8*)(qp + quad * 8);
    aq[m][1] = *(const bf16x8*)(qp + 32 + quad * 8);
  }
  f32x4 oacc[4][4] = {};
  float lrow[4][4] = {};
  const int permr = 2 * (row_in >> 2) + (row_in & 1) + 8 * ((row_in >> 1) & 1);
  const int pw_base = (w * 64) * 72;

  for (int kt = 0; kt < SS / 64; ++kt) {
    __syncthreads();
    const size_t kbase = ((size_t)(b * SS + kt * 64)) * DD + h * 64;
#pragma unroll
    for (int i = 0; i < 2; ++i) {
      int c = tid + i * 256, r = c >> 3, o8 = (c & 7) * 8;
      *(uint4*)(Ks + r * 72 + o8) = *(const uint4*)(K + kbase + (size_t)r * DD + o8);
      *(uint4*)(Vs + r * 72 + o8) =
          *(const uint4*)(Vt_g + ((size_t)(bh * 64 + r)) * SS + kt * 64 + o8);
    }
    __syncthreads();

    bf16x8 bk[4][2];
#pragma unroll
    for (int n = 0; n < 4; ++n) {
      bk[n][0] = *(const bf16x8*)(Ks + (n * 16 + row_in) * 72 + quad * 8);
      bk[n][1] = *(const bf16x8*)(Ks + (n * 16 + row_in) * 72 + 32 + quad * 8);
    }

#pragma unroll
    for (int m = 0; m < 4; ++m) {
      // S = Q K^T : 16q x 64key
      f32x4 sa[4] = {};
#pragma unroll
      for (int n = 0; n < 4; ++n) {
        sa[n] = __builtin_amdgcn_mfma_f32_16x16x32_bf16(aq[m][0], bk[n][0], sa[n], 0, 0, 0);
        sa[n] = __builtin_amdgcn_mfma_f32_16x16x32_bf16(aq[m][1], bk[n][1], sa[n], 0, 0, 0);
      }
      // fixed-shift softmax; writer's keys {n*16+row_in} land at sigma = row_in*4+n
#pragma unroll
      for (int r = 0; r < 4; ++r) {
        int prow = pw_base + (m * 16 + 2 * quad + (r & 1) + 8 * ((r >> 1) & 1)) * 72;
        union { float f; unsigned u; } p0, p1, p2, p3;
        p0.f = __builtin_amdgcn_exp2f(fmaf(sa[0][r], Cs, -C0));
        p1.f = __builtin_amdgcn_exp2f(fmaf(sa[1][r], Cs, -C0));
        p2.f = __builtin_amdgcn_exp2f(fmaf(sa[2][r], Cs, -C0));
        p3.f = __builtin_amdgcn_exp2f(fmaf(sa[3][r], Cs, -C0));
        lrow[m][r] += (p0.f + p1.f) + (p2.f + p3.f);
        unsigned w01 = __builtin_amdgcn_perm(p1.u + 0x8000u, p0.u + 0x8000u, 0x07060302);
        unsigned w23 = __builtin_amdgcn_perm(p3.u + 0x8000u, p2.u + 0x8000u, 0x07060302);
        *(uint2*)(Ps + prow + row_in * 4) = make_uint2(w01, w23);
      }
    }

    // O += P V over sigma-space (wave-private P stripe -> no barrier)
#pragma unroll
    for (int c = 0; c < 2; ++c) {
#pragma unroll
      for (int t = 0; t < 4; ++t) {
        bf16x8 bv = *(const bf16x8*)(Vs + (t * 16 + row_in) * 72 + c * 32 + quad * 8);
#pragma unroll
        for (int m = 0; m < 4; ++m) {
          bf16x8 ap = *(const bf16x8*)(Ps + pw_base + (m * 16 + permr) * 72 + c * 32 + quad * 8);
          oacc[m][t] = __builtin_amdgcn_mfma_f32_16x16x32_bf16(ap, bv, oacc[m][t], 0, 0, 0);
        }
      }
    }
  }

#pragma unroll
  for (int m = 0; m < 4; ++m)
#pragma unroll
    for (int r = 0; r < 4; ++r) {
#pragma unroll
      for (int s = 1; s < 16; s <<= 1) lrow[m][r] += __shfl_xor(lrow[m][r], s, 64);
      float inv = 1.0f / lrow[m][r];
#pragma unroll
      for (int t = 0; t < 4; ++t)
        AO[qbase + (size_t)(w * 64 + m * 16 + quad * 4 + r) * DD + t * 16 + row_in] =
            f2bf(oacc[m][t][r] * inv);
    }
}

extern "C" void kernel_launch(void* const* d_in, const int* in_sizes, int n_in,
                              void* d_out, int out_size, void* d_ws, size_t ws_size,
                              hipStream_t stream) {
  const float* X  = (const float*)d_in[0];
  const float* Wq = (const float*)d_in[1];
  const float* Wk = (const float*)d_in[2];
  const float* Wv = (const float*)d_in[3];
  const float* Wo = (const float*)d_in[4];

  unsigned short* ws   = (unsigned short*)d_ws;
  unsigned short* Qb   = ws;                           // 16 MiB — also AO
  unsigned short* Kb   = Qb + (size_t)MM * DD;         // 16 MiB
  unsigned short* Vtb  = Kb + (size_t)MM * DD;         // 16 MiB, [bh][d][sigma(s)]
  unsigned short* Wall = Vtb + (size_t)MM * DD;        // 8 MiB (Wq,Wk,Wv,Wo bf16)
  unsigned short* Xb   = (unsigned short*)d_out;       // 16 MiB scratch inside d_out
  float* out = (float*)d_out;

  convall<<<dim3(1024, 12), 256, 0, stream>>>(X, Wq, Wk, Wv, Wo, Wall, Xb);

  gemm_k<3><<<dim3(MM / 128, 24), 256, 0, stream>>>(Xb, Wall, Qb, Kb, Vtb);

  attn_kernel<<<dim3(SS / 256, BB * HH), 256, 0, stream>>>(Qb, Kb, Vtb, Qb);

  gemm_k<1><<<dim3(MM / 128, 8), 256, 0, stream>>>(Qb, Wall + (size_t)3 * 1048576,
                                                   out, nullptr, nullptr);
}

// Round 8
// 278.772 us; speedup vs baseline: 1.0382x; 1.0382x over previous
//
#include <hip/hip_runtime.h>
#include <hip/hip_bf16.h>

#define BB 4
#define SS 2048
#define DD 1024
#define HH 16
#define MM (BB * SS)   // 8192

typedef __attribute__((ext_vector_type(8))) short bf16x8;
typedef __attribute__((ext_vector_type(4))) float f32x4;

__device__ __forceinline__ unsigned short f2bf(float f) {
  union { float f; unsigned u; } v; v.f = f;
  unsigned r = v.u + 0x7fffu + ((v.u >> 16) & 1u);
  return (unsigned short)(r >> 16);
}

__device__ __forceinline__ void gl2lds16(const void* g, void* l) {
  __builtin_amdgcn_global_load_lds(
      (const __attribute__((address_space(1))) unsigned int*)g,
      (__attribute__((address_space(3))) unsigned int*)l, 16, 0, 0);
}

// fp32 -> bf16 pre-convert: y<4 -> W[y] (1M each), y>=4 -> X chunk (8M total)
__global__ __launch_bounds__(256)
void convall(const float* __restrict__ X, const float* __restrict__ a,
             const float* __restrict__ b, const float* __restrict__ c,
             const float* __restrict__ d, unsigned short* __restrict__ wall,
             unsigned short* __restrict__ xb) {
  int y = blockIdx.y;
  const float* s; unsigned short* o;
  if (y < 4) {
    const float* srcs[4] = {a, b, c, d};
    s = srcs[y]; o = wall + (size_t)y * 1048576;
  } else {
    s = X + (size_t)(y - 4) * 1048576; o = xb + (size_t)(y - 4) * 1048576;
  }
  int i = (blockIdx.x * 256 + threadIdx.x) * 4;
  float4 v = *(const float4*)(s + i);
  ushort4 h4; h4.x = f2bf(v.x); h4.y = f2bf(v.y); h4.z = f2bf(v.z); h4.w = f2bf(v.w);
  *(ushort4*)(o + i) = h4;
}

// C[m,n] = sum_k A[m,k]*W[n,k].  A bf16, B bf16, both staged via global_load_lds w=16.
// 1-D grid with XCD-aware panel swizzle: bid%8 = m-offset within 8-m panel (pins each
// m-tile's A-panel to one XCD's L2 across all n-steps), (bid/8)%NT = n-tile.
// OMODE 1: fp32 C (NT=8).  OMODE 3: QKV routing (NT=24; Q bf16 / K bf16 / V -> sigma-
// permuted V^T, Vt[bh][d][kt*64 + sigma(key)], sigma(key) = (key&15)*4 + (key>>4)).
template<int OMODE>
__global__ __launch_bounds__(256)
void gemm_k(const unsigned short* __restrict__ A16, const unsigned short* __restrict__ Bp,
            void* __restrict__ C0p, void* __restrict__ C1p, void* __restrict__ C2p) {
  __shared__ unsigned short As[32 * 136];  // staging [128][32]; also V^T transpose buf
  __shared__ unsigned short Bs[128 * 32];
  constexpr int NT = (OMODE == 3) ? 24 : 8;
  const int bid = blockIdx.x;
  const int panel = bid / (8 * NT), within = bid % (8 * NT);
  const int m0 = (panel * 8 + (within & 7)) * 128, n0g = (within >> 3) * 128;
  const int tid = threadIdx.x, lane = tid & 63, wave = tid >> 6;
  const int wm = (wave & 1) * 64, wn = (wave >> 1) * 64;
  const int row_in = lane & 15, quad = lane >> 4;

  f32x4 acc[4][4] = {};

  for (int kb = 0; kb < DD; kb += 32) {
    {
      int r = wave * 32 + (lane >> 2);
      const unsigned short* g = Bp + (size_t)(n0g + r) * DD + kb + (lane & 3) * 8;
      gl2lds16(g, Bs + (wave * 32) * 32);
      gl2lds16(g + (size_t)16 * DD, Bs + (wave * 32 + 16) * 32);
      const unsigned short* ga = A16 + (size_t)(m0 + r) * DD + kb + (lane & 3) * 8;
      gl2lds16(ga, As + (wave * 32) * 32);
      gl2lds16(ga + (size_t)16 * DD, As + (wave * 32 + 16) * 32);
    }
    __syncthreads();
    bf16x8 af[4], bfr[4];
#pragma unroll
    for (int i = 0; i < 4; ++i)
      af[i] = *(const bf16x8*)(As + (wm + i * 16 + row_in) * 32 + quad * 8);
#pragma unroll
    for (int j = 0; j < 4; ++j)
      bfr[j] = *(const bf16x8*)(Bs + (wn + j * 16 + row_in) * 32 + quad * 8);
#pragma unroll
    for (int i = 0; i < 4; ++i)
#pragma unroll
      for (int j = 0; j < 4; ++j)
        acc[i][j] = __builtin_amdgcn_mfma_f32_16x16x32_bf16(af[i], bfr[j], acc[i][j], 0, 0, 0);
    __syncthreads();
  }

  // C/D layout: col = lane&15, row = quad*4 + reg
  if (OMODE == 1) {
    float* Cout = (float*)C0p;
#pragma unroll
    for (int i = 0; i < 4; ++i)
#pragma unroll
      for (int j = 0; j < 4; ++j)
#pragma unroll
        for (int r = 0; r < 4; ++r)
          Cout[(size_t)(m0 + wm + i * 16 + quad * 4 + r) * DD + n0g + wn + j * 16 + row_in] =
              acc[i][j][r];
  } else {
    const int seg = n0g >> 10;
    if (seg < 2) {
      unsigned short* Cout = (unsigned short*)(seg == 0 ? C0p : C1p);
      const int n0 = n0g & 1023;
#pragma unroll
      for (int i = 0; i < 4; ++i)
#pragma unroll
        for (int j = 0; j < 4; ++j)
#pragma unroll
          for (int r = 0; r < 4; ++r)
            Cout[(size_t)(m0 + wm + i * 16 + quad * 4 + r) * DD + n0 + wn + j * 16 + row_in] =
                f2bf(acc[i][j][r]);
    } else {
      // V^T epilogue -> Vt[bh][d][kt*64 + sigma(key)].  Stored position p holds
      // key sigma^-1(p) = (p&3)*16 + (p>>2): gather cols from the transpose buffer.
      unsigned short* Vt = (unsigned short*)C2p;
      unsigned short* Ts = As;
      const int b = m0 >> 11, m_in_b = m0 & 2047;
      const int nv = n0g - 2048;
#pragma unroll
      for (int cn = 0; cn < 4; ++cn) {
        if ((wave >> 1) == (cn >> 1)) {
#pragma unroll
          for (int i = 0; i < 4; ++i)
#pragma unroll
            for (int jj = 0; jj < 2; ++jj)
#pragma unroll
              for (int r = 0; r < 4; ++r) {
                int j = (cn & 1) * 2 + jj;
                Ts[(jj * 16 + row_in) * 136 + wm + i * 16 + quad * 4 + r] = f2bf(acc[i][j][r]);
              }
        }
        __syncthreads();
#pragma unroll
        for (int it = 0; it < 2; ++it) {
          int cc = tid + it * 256;
          int rowL = cc >> 4, o8 = (cc & 15) * 8;
          int cbase = rowL * 136 + (o8 & 64) + ((o8 & 63) >> 2);
          ushort4 lo, hi;
          lo.x = Ts[cbase];      lo.y = Ts[cbase + 16];
          lo.z = Ts[cbase + 32]; lo.w = Ts[cbase + 48];
          hi.x = Ts[cbase + 1];  hi.y = Ts[cbase + 17];
          hi.z = Ts[cbase + 33]; hi.w = Ts[cbase + 49];
          int n = nv + cn * 32 + rowL;
          int h = n >> 6, dd = n & 63;
          unsigned short* dst = Vt + ((size_t)((b * 16 + h) * 64 + dd)) * SS + m_in_b + o8;
          *(ushort4*)dst = lo;
          *(ushort4*)(dst + 4) = hi;
        }
        __syncthreads();
      }
    }
  }
}

// Flash attention (R6-proven config): block = 128 q-rows x one (b,h); 4 waves x 32
// q-rows; 4 blocks/CU.  V sigma-pre-permuted in global -> plain vector-copy staging.
// Fixed-shift softmax; P via wave-private sigma-keyed LDS stripes.  AO in-place over Q.
__global__ __launch_bounds__(256, 4)
void attn_kernel(const unsigned short* __restrict__ Q, const unsigned short* __restrict__ K,
                 const unsigned short* __restrict__ Vt_g, unsigned short* __restrict__ AO) {
  __shared__ unsigned short Ks[64 * 72];   // [key][d]
  __shared__ unsigned short Vs[64 * 72];   // [d][sigma(key)]
  __shared__ unsigned short Ps[128 * 72];  // [q perm][sigma(key)]
  const int qt = blockIdx.x, bh = blockIdx.y, b = bh >> 4, h = bh & 15;
  const int tid = threadIdx.x, lane = tid & 63, w = tid >> 6;
  const int row_in = lane & 15, quad = lane >> 4;
  const float Cs = 0.180336880f;   // log2e / 8
  const float C0 = 17.3123405f;    // 12 * log2e
  const size_t qbase = ((size_t)(b * SS + qt * 128)) * DD + h * 64;

  bf16x8 aq[2][2];
#pragma unroll
  for (int m = 0; m < 2; ++m) {
    const unsigned short* qp = Q + qbase + (size_t)(w * 32 + m * 16 + row_in) * DD;
    aq[m][0] = *(const bf16x8*)(qp + quad * 8);
    aq[m][1] = *(const bf16x8*)(qp + 32 + quad * 8);
  }
  f32x4 oacc[2][4] = {};
  float lrow[2][4] = {};
  const int permr = 2 * (row_in >> 2) + (row_in & 1) + 8 * ((row_in >> 1) & 1);
  const int pw_base = (w * 32) * 72;

  for (int kt = 0; kt < SS / 64; ++kt) {
    __syncthreads();
    const size_t kbase = ((size_t)(b * SS + kt * 64)) * DD + h * 64;
#pragma unroll
    for (int i = 0; i < 2; ++i) {
      int c = tid + i * 256, r = c >> 3, o8 = (c & 7) * 8;
      *(uint4*)(Ks + r * 72 + o8) = *(const uint4*)(K + kbase + (size_t)r * DD + o8);
      *(uint4*)(Vs + r * 72 + o8) =
          *(const uint4*)(Vt_g + ((size_t)(bh * 64 + r)) * SS + kt * 64 + o8);
    }
    __syncthreads();

    // S = Q K^T : 32q x 64key per wave
    f32x4 sacc[2][4] = {};
#pragma unroll
    for (int n = 0; n < 4; ++n) {
      bf16x8 bk0 = *(const bf16x8*)(Ks + (n * 16 + row_in) * 72 + quad * 8);
      bf16x8 bk1 = *(const bf16x8*)(Ks + (n * 16 + row_in) * 72 + 32 + quad * 8);
#pragma unroll
      for (int m = 0; m < 2; ++m) {
        sacc[m][n] = __builtin_amdgcn_mfma_f32_16x16x32_bf16(aq[m][0], bk0, sacc[m][n], 0, 0, 0);
        sacc[m][n] = __builtin_amdgcn_mfma_f32_16x16x32_bf16(aq[m][1], bk1, sacc[m][n], 0, 0, 0);
      }
    }

    // fixed-shift softmax: p = exp2(s*Cs - C0); writer's keys {n*16+row_in} land
    // at sigma = row_in*4+n -> one b64 write per (m,r)
#pragma unroll
    for (int m = 0; m < 2; ++m)
#pragma unroll
      for (int r = 0; r < 4; ++r) {
        int prow = pw_base + (m * 16 + 2 * quad + (r & 1) + 8 * ((r >> 1) & 1)) * 72;
        union { float f; unsigned u; } p0, p1, p2, p3;
        p0.f = __builtin_amdgcn_exp2f(fmaf(sacc[m][0][r], Cs, -C0));
        p1.f = __builtin_amdgcn_exp2f(fmaf(sacc[m][1][r], Cs, -C0));
        p2.f = __builtin_amdgcn_exp2f(fmaf(sacc[m][2][r], Cs, -C0));
        p3.f = __builtin_amdgcn_exp2f(fmaf(sacc[m][3][r], Cs, -C0));
        lrow[m][r] += (p0.f + p1.f) + (p2.f + p3.f);
        unsigned w01 = __builtin_amdgcn_perm(p1.u + 0x8000u, p0.u + 0x8000u, 0x07060302);
        unsigned w23 = __builtin_amdgcn_perm(p3.u + 0x8000u, p2.u + 0x8000u, 0x07060302);
        *(uint2*)(Ps + prow + row_in * 4) = make_uint2(w01, w23);
      }

    // O += P V over sigma-space (wave-private P rows -> no barrier)
#pragma unroll
    for (int c = 0; c < 2; ++c) {
      bf16x8 ap0 = *(const bf16x8*)(Ps + pw_base + (permr) * 72 + c * 32 + quad * 8);
      bf16x8 ap1 = *(const bf16x8*)(Ps + pw_base + (16 + permr) * 72 + c * 32 + quad * 8);
#pragma unroll
      for (int t = 0; t < 4; ++t) {
        bf16x8 bv = *(const bf16x8*)(Vs + (t * 16 + row_in) * 72 + c * 32 + quad * 8);
        oacc[0][t] = __builtin_amdgcn_mfma_f32_16x16x32_bf16(ap0, bv, oacc[0][t], 0, 0, 0);
        oacc[1][t] = __builtin_amdgcn_mfma_f32_16x16x32_bf16(ap1, bv, oacc[1][t], 0, 0, 0);
      }
    }
  }

#pragma unroll
  for (int m = 0; m < 2; ++m)
#pragma unroll
    for (int r = 0; r < 4; ++r) {
#pragma unroll
      for (int s = 1; s < 16; s <<= 1) lrow[m][r] += __shfl_xor(lrow[m][r], s, 64);
      float inv = 1.0f / lrow[m][r];
#pragma unroll
      for (int t = 0; t < 4; ++t)
        AO[qbase + (size_t)(w * 32 + m * 16 + quad * 4 + r) * DD + t * 16 + row_in] =
            f2bf(oacc[m][t][r] * inv);
    }
}

extern "C" void kernel_launch(void* const* d_in, const int* in_sizes, int n_in,
                              void* d_out, int out_size, void* d_ws, size_t ws_size,
                              hipStream_t stream) {
  const float* X  = (const float*)d_in[0];
  const float* Wq = (const float*)d_in[1];
  const float* Wk = (const float*)d_in[2];
  const float* Wv = (const float*)d_in[3];
  const float* Wo = (const float*)d_in[4];

  unsigned short* ws   = (unsigned short*)d_ws;
  unsigned short* Qb   = ws;                           // 16 MiB — also AO
  unsigned short* Kb   = Qb + (size_t)MM * DD;         // 16 MiB
  unsigned short* Vtb  = Kb + (size_t)MM * DD;         // 16 MiB, [bh][d][sigma(s)]
  unsigned short* Wall = Vtb + (size_t)MM * DD;        // 8 MiB (Wq,Wk,Wv,Wo bf16)
  unsigned short* Xb   = (unsigned short*)d_out;       // 16 MiB scratch inside d_out
  float* out = (float*)d_out;

  convall<<<dim3(1024, 12), 256, 0, stream>>>(X, Wq, Wk, Wv, Wo, Wall, Xb);

  gemm_k<3><<<dim3(64 * 24), 256, 0, stream>>>(Xb, Wall, Qb, Kb, Vtb);

  attn_kernel<<<dim3(SS / 128, BB * HH), 256, 0, stream>>>(Qb, Kb, Vtb, Qb);

  gemm_k<1><<<dim3(64 * 8), 256, 0, stream>>>(Qb, Wall + (size_t)3 * 1048576,
                                              out, nullptr, nullptr);
}